// Round 5
// baseline (227.631 us; speedup 1.0000x reference)
//
#include <hip/hip_runtime.h>
#include <hip/hip_bf16.h>
#include <math.h>

// Problem constants: B=32 V=512 K=16 D=128 E=32 NE=8192 -> BV=16384 vertices
// Block = 8 vertices (4 pairs), grid 2048. LDS 25.8KB -> 6 blocks/CU = 24 waves/CU.
#define NLSTR 136   // LDS row stride (ushorts) for 8x128 tiles
#define ASTR  168   // LDS row stride (ushorts) for A tiles: 160+8 pad, 336B (16B-aligned)

typedef __bf16 bf16x8 __attribute__((ext_vector_type(8)));
typedef float f32x4 __attribute__((ext_vector_type(4)));
typedef float f32x16 __attribute__((ext_vector_type(16)));
typedef unsigned short ushort8v __attribute__((ext_vector_type(8)));

union FragU { ushort8v u; bf16x8 b; };

static __device__ inline unsigned short f2bf(float f){
  unsigned u = __float_as_uint(f);
  u += 0x7fffu + ((u >> 16) & 1u);   // RNE
  return (unsigned short)(u >> 16);
}
static __device__ inline float bf2f(unsigned short u){
  return __uint_as_float(((unsigned)u) << 16);
}
static __device__ inline unsigned pk2(float a, float b){
  union { __hip_bfloat162 h; unsigned u; } r;
  r.h = __float22bfloat162_rn(float2{a, b});
  return r.u;
}
static __device__ inline ushort8v pkcvt8(float4 a, float4 b){
  union { unsigned u[4]; ushort8v v; } r;
  r.u[0] = pk2(a.x, a.y); r.u[1] = pk2(a.z, a.w);
  r.u[2] = pk2(b.x, b.y); r.u[3] = pk2(b.z, b.w);
  return r.v;
}

// tanh-form GELU (max err ~3e-4 vs exact erf-GELU).
// exp2 scale (-1/ln2) folded into the polynomial constants.
static __device__ inline float gelu_f(float x){
  float u = x * x;
  float p = fmaf(u, -0.1029434273f, -2.3022084765f);
  float e = __builtin_amdgcn_exp2f(x * p);
  return x * __builtin_amdgcn_rcpf(1.0f + e);
}

// Raw barrier: publishes own LDS writes (lgkmcnt drain) WITHOUT draining vmcnt.
#define WG_BARRIER() asm volatile("s_waitcnt lgkmcnt(0)\n\ts_barrier" ::: "memory")

// ---------------- prep: bf16 vertex table + fragment-order bf16 weights ----------------
__global__ __launch_bounds__(256) void prep_kernel(
    const float* __restrict__ vf, const float* __restrict__ W1,
    const float* __restrict__ W2, const float* __restrict__ W3,
    unsigned short* __restrict__ vfbf, unsigned short* __restrict__ w1f,
    unsigned short* __restrict__ w2f, unsigned short* __restrict__ w3f)
{
  int t = blockIdx.x * 256 + threadIdx.x;
  if (t < 262144){                       // 16384*128 / 8
    const float4* src = (const float4*)vf;
    float4 x = src[t * 2], y = src[t * 2 + 1];
    *(ushort8v*)(vfbf + t * 8) = pkcvt8(x, y);
    return;
  }
  int t2 = t - 262144;
  const float* s;
  unsigned short* d;
  if (t2 < 2560){                        // w1f: 4nc2 x 10kc strip-major
    int fragid = t2 >> 6, lane = t2 & 63;
    int nc2 = fragid / 10, kc = fragid % 10, n = lane & 31, h = lane >> 5;
    s = W1 + (nc2 * 32 + n) * 160 + kc * 16 + h * 8;
    d = w1f + t2 * 8;
  } else if (t2 < 6656){                 // w2f: 8kc x 8nc
    int t3 = t2 - 2560;
    int fragid = t3 >> 6, lane = t3 & 63;
    int kc = fragid >> 3, nc = fragid & 7, col = lane & 15, quad = lane >> 4;
    s = W2 + (nc * 16 + col) * 256 + kc * 32 + quad * 8;
    d = w2f + t3 * 8;
  } else if (t2 < 8704){                 // w3f: 4kc x 8nc
    int t3 = t2 - 6656;
    int fragid = t3 >> 6, lane = t3 & 63;
    int kc = fragid >> 3, nc = fragid & 7, col = lane & 15, quad = lane >> 4;
    s = W3 + (nc * 16 + col) * 128 + kc * 32 + quad * 8;
    d = w3f + t3 * 8;
  } else return;
#pragma unroll
  for (int j = 0; j < 8; j++) d[j] = f2bf(s[j]);
}

// ---------------- fused ----------------
// grid 2048 x 256thr. Block = 8 vertices = 4 pairs. R1-proven rolling schedule:
// issue g(p+2) at iter p, commit at iter p+1; WG_BARRIER keeps gathers in flight.
// LDS 25.8KB + ~64 VGPR -> 6 blocks/CU (24 waves): when one block stalls on
// gather/barrier, 5 other independent blocks issue. setprio(1) around the MFMA
// chain (T5: 6 independent barrier groups = wave role diversity). Accumulator
// initialized with b1 (bias folded into MFMA C-in).
__global__ __launch_bounds__(256, 6) void fused_kernel(
    const unsigned short* __restrict__ vfbf,
    const float* __restrict__ vf,
    const int* __restrict__ aadj, const int* __restrict__ badj,
    const float* __restrict__ edge, const float* __restrict__ nbs,
    const float* __restrict__ h0,
    const unsigned short* __restrict__ w1f, const unsigned short* __restrict__ w2f,
    const unsigned short* __restrict__ w3f,
    const float* __restrict__ b1, const float* __restrict__ b2, const float* __restrict__ b3,
    const float* __restrict__ lamda, const float* __restrict__ alpha,
    const int* __restrict__ lval,
    float* __restrict__ out)
{
  __shared__ __align__(16) unsigned short abuf[2][32 * ASTR];   // 2 x 10.5 KB
  __shared__ __align__(16) unsigned short nl_lds[8 * NLSTR];    // 2.1 KB
  __shared__ __align__(16) unsigned short sup_lds[8 * NLSTR];   // 2.1 KB
  __shared__ __align__(16) float nbs_lds[128];                  // 8 vertices x 16 masks
  const int wid  = threadIdx.x >> 6;
  const int lane = threadIdx.x & 63;
  const int n32  = lane & 31;
  const int h    = lane >> 5;
  const int col  = lane & 15;
  const int quad = lane >> 4;
  const int v0   = blockIdx.x * 8;

  // staging thread mapping: 8 threads per A row
  const int srow = threadIdx.x >> 3;   // 0..31: row (vertex-half + neighbor slot)
  const int ssub = threadIdx.x & 7;    // 0..7

  // ---- stage this block's nbs masks into LDS (published by first barrier) ----
  if (threadIdx.x < 128) nbs_lds[threadIdx.x] = nbs[v0 * 16 + threadIdx.x];

  // ---- preload all pair indices (coalesced) ----
  int a_all[4], e_all[4];
  {
    const int base = (v0 + (srow >> 4)) * 16 + (srow & 15);
#pragma unroll
    for (int p = 0; p < 4; p++){
      a_all[p] = aadj[base + 32 * p];
      e_all[p] = badj[base + 32 * p];
    }
  }

  // ---- B strip into registers (wave wid -> nc2 = wid) ----
  FragU bw[10];
#pragma unroll
  for (int kc = 0; kc < 10; kc++)
    bw[kc].u = *(const ushort8v*)(w1f + ((wid * 10 + kc) * 64 + lane) * 8);

  const float bb1 = b1[wid * 32 + n32];

  ushort8v sv0, sv1; float4 se;
  // issue pair-0 gathers
  {
    const ushort8v* vs = (const ushort8v*)(vfbf + (size_t)a_all[0] * 128 + ssub * 16);
    sv0 = vs[0]; sv1 = vs[1];
    se = *(const float4*)(edge + (size_t)e_all[0] * 32 + ssub * 4);
  }
  // commit pair-0 into abuf[0]
  {
    unsigned short* dst = abuf[0] + srow * ASTR + ssub * 16;
    *(ushort8v*)dst = sv0; *(ushort8v*)(dst + 8) = sv1;
    unsigned* ed = (unsigned*)(abuf[0] + srow * ASTR + 128 + ssub * 4);
    ed[0] = pk2(se.x, se.y); ed[1] = pk2(se.z, se.w);
  }
  // issue pair-1 gathers
  {
    const ushort8v* vs = (const ushort8v*)(vfbf + (size_t)a_all[1] * 128 + ssub * 16);
    sv0 = vs[0]; sv1 = vs[1];
    se = *(const float4*)(edge + (size_t)e_all[1] * 32 + ssub * 4);
  }

  const float4* nbsl = (const float4*)nbs_lds;

#pragma unroll
  for (int p = 0; p < 4; ++p){
    WG_BARRIER();   // publish pair p (and nbs_lds at p=0); in-flight gathers survive

    // ---- commit pair p+1 (gathers ~1 compute phase old) ----
    if (p < 3){
      unsigned short* dst = abuf[(p + 1) & 1] + srow * ASTR + ssub * 16;
      *(ushort8v*)dst = sv0; *(ushort8v*)(dst + 8) = sv1;
      unsigned* ed = (unsigned*)(abuf[(p + 1) & 1] + srow * ASTR + 128 + ssub * 4);
      ed[0] = pk2(se.x, se.y); ed[1] = pk2(se.z, se.w);
    }
    // ---- issue gathers for pair p+2 ----
    if (p < 2){
      const ushort8v* vs = (const ushort8v*)(vfbf + (size_t)a_all[p + 2] * 128 + ssub * 16);
      sv0 = vs[0]; sv1 = vs[1];
      se = *(const float4*)(edge + (size_t)e_all[p + 2] * 32 + ssub * 4);
    }

    // ---- hoisted mask reads (LDS broadcast) ----
    const float4 mAlo = nbsl[8 * p + h],     mAhi = nbsl[8 * p + 2 + h];
    const float4 mBlo = nbsl[8 * p + 4 + h], mBhi = nbsl[8 * p + 6 + h];

    // ---- pair-p MFMA: A from LDS, B from registers; C-in = b1 bias ----
    const unsigned short* ab = abuf[p & 1] + n32 * ASTR + h * 8;
    f32x16 acc;
#pragma unroll
    for (int j = 0; j < 16; j++) acc[j] = bb1;
    __builtin_amdgcn_s_setprio(1);
#pragma unroll
    for (int kc = 0; kc < 10; kc++){
      FragU fa;
      fa.u = *(const ushort8v*)(ab + kc * 16);
      acc = __builtin_amdgcn_mfma_f32_32x32x16_bf16(fa.b, bw[kc].b, acc, 0, 0, 0);
    }
    __builtin_amdgcn_s_setprio(0);

    // ---- epilogue: GELU, mask, reduce; C row=(reg&3)+8*(reg>>2)+4*h ----
    {
      float sA = fmaf(gelu_f(acc[0]), mAlo.x, gelu_f(acc[1]) * mAlo.y)
               + fmaf(gelu_f(acc[2]), mAlo.z, gelu_f(acc[3]) * mAlo.w)
               + fmaf(gelu_f(acc[4]), mAhi.x, gelu_f(acc[5]) * mAhi.y)
               + fmaf(gelu_f(acc[6]), mAhi.z, gelu_f(acc[7]) * mAhi.w);
      float sB = fmaf(gelu_f(acc[8]), mBlo.x, gelu_f(acc[9]) * mBlo.y)
               + fmaf(gelu_f(acc[10]), mBlo.z, gelu_f(acc[11]) * mBlo.w)
               + fmaf(gelu_f(acc[12]), mBhi.x, gelu_f(acc[13]) * mBhi.y)
               + fmaf(gelu_f(acc[14]), mBhi.z, gelu_f(acc[15]) * mBhi.w);
      sA += __shfl_xor(sA, 32, 64);
      sB += __shfl_xor(sB, 32, 64);
      if (h == 0) nl_lds[(2 * p)     * NLSTR + wid * 32 + n32] = f2bf(sA);
      else        nl_lds[(2 * p + 1) * NLSTR + wid * 32 + n32] = f2bf(sB);
    }
  }
  __syncthreads();

  // ---------------- stage 2: wave wid computes output cols [wid*32, wid*32+32) --------
  // 16x16 MFMA tiles; block has only 8 vertex rows -> rows 8-15 fold onto 0-7
  // (col&7): duplicate C rows, discarded by the quad<2 write guards. No OOB.
  const int nc0 = 2 * wid;
  const float th = logf(lamda[0] / (float)lval[0] + 1.0f);
  const float al = alpha[0];
  const int vrow = quad * 4;           // 0,4,8,12; valid rows are vrow<8 (quad<2)

  // hoist h0 loads (fold invalid rows onto valid ones; values discarded)
  float h0v[2][4];
#pragma unroll
  for (int pq = 0; pq < 2; pq++){
    const int d = (nc0 + pq) * 16 + col;
#pragma unroll
    for (int r = 0; r < 4; r++)
      h0v[pq][r] = h0[(v0 + ((vrow + r) & 7)) * 128 + d];
  }

  f32x4 acc2[2] = {};
#pragma unroll
  for (int kc = 0; kc < 8; kc++){
    FragU a;
    if (kc < 4) a.u = *(const ushort8v*)(nl_lds + (col & 7) * NLSTR + kc * 32 + quad * 8);
    else        a.u = *(const ushort8v*)(vfbf + (size_t)(v0 + (col & 7)) * 128 + (kc - 4) * 32 + quad * 8);
#pragma unroll
    for (int pq = 0; pq < 2; pq++){
      FragU bf_;
      bf_.u = *(const ushort8v*)(w2f + ((kc * 8 + nc0 + pq) * 64 + lane) * 8);
      acc2[pq] = __builtin_amdgcn_mfma_f32_16x16x32_bf16(a.b, bf_.b, acc2[pq], 0, 0, 0);
    }
  }

  float sup[2][4];
#pragma unroll
  for (int pq = 0; pq < 2; pq++){
    const int d = (nc0 + pq) * 16 + col;
    const float bb = b2[d];
#pragma unroll
    for (int r = 0; r < 4; r++){
      float hi = acc2[pq][r] + bb;
      float s = (1.f - al) * hi + al * h0v[pq][r];
      sup[pq][r] = s;
      if (quad < 2) sup_lds[(vrow + r) * NLSTR + d] = f2bf(s);
    }
  }
  __syncthreads();

  // hoist fp32 residual loads (folded rows; discarded for quad>=2)
  float rv[2][4];
#pragma unroll
  for (int pq = 0; pq < 2; pq++){
    const int d = (nc0 + pq) * 16 + col;
#pragma unroll
    for (int r = 0; r < 4; r++)
      rv[pq][r] = vf[(size_t)(v0 + ((vrow + r) & 7)) * 128 + d];
  }

  f32x4 acc3[2] = {};
#pragma unroll
  for (int kc = 0; kc < 4; kc++){
    FragU a;
    a.u = *(const ushort8v*)(sup_lds + (col & 7) * NLSTR + kc * 32 + quad * 8);
#pragma unroll
    for (int pq = 0; pq < 2; pq++){
      FragU bf_;
      bf_.u = *(const ushort8v*)(w3f + ((kc * 8 + nc0 + pq) * 64 + lane) * 8);
      acc3[pq] = __builtin_amdgcn_mfma_f32_16x16x32_bf16(a.b, bf_.b, acc3[pq], 0, 0, 0);
    }
  }

  if (quad < 2){
#pragma unroll
    for (int pq = 0; pq < 2; pq++){
      const int d = (nc0 + pq) * 16 + col;
      const float bb = b3[d];
#pragma unroll
      for (int r = 0; r < 4; r++){
        const int vtx = v0 + vrow + r;
        out[vtx * 128 + d] = th * (acc3[pq][r] + bb) + (1.f - th) * sup[pq][r] + rv[pq][r];
      }
    }
  }
}

extern "C" void kernel_launch(void* const* d_in, const int* in_sizes, int n_in,
                              void* d_out, int out_size, void* d_ws, size_t ws_size,
                              hipStream_t stream)
{
  const float* vfp  = (const float*)d_in[0];
  const int*   aadj = (const int*)d_in[1];
  const int*   badj = (const int*)d_in[2];
  const float* h0   = (const float*)d_in[3];
  const float* lam  = (const float*)d_in[4];
  const float* alp  = (const float*)d_in[5];
  const int*   lv   = (const int*)d_in[6];
  const float* edge = (const float*)d_in[7];
  // d_in[8] vertex_mask: unused by the reference math
  const float* nbs  = (const float*)d_in[9];
  const float* W1   = (const float*)d_in[10];
  const float* b1   = (const float*)d_in[11];
  const float* W2   = (const float*)d_in[12];
  const float* b2   = (const float*)d_in[13];
  const float* W3   = (const float*)d_in[14];
  const float* b3   = (const float*)d_in[15];
  float* out = (float*)d_out;

  // ws layout (ushorts): w1f [0,20480) | w2f [20480,53248) | w3f [53248,69632)
  //                      | vfbf [69632, 69632+2097152)
  unsigned short* w1f  = (unsigned short*)d_ws;
  unsigned short* w2f  = w1f + 20480;
  unsigned short* w3f  = w2f + 32768;
  unsigned short* vfbf = w3f + 16384;

  prep_kernel<<<1058, 256, 0, stream>>>(vfp, W1, W2, W3, vfbf, w1f, w2f, w3f);
  fused_kernel<<<2048, 256, 0, stream>>>(vfbf, vfp, aadj, badj, edge, nbs, h0,
                                         w1f, w2f, w3f, b1, b2, b3, lam, alp, lv, out);
}

// Round 6
// 168.949 us; speedup vs baseline: 1.3473x; 1.3473x over previous
//
#include <hip/hip_runtime.h>
#include <hip/hip_bf16.h>
#include <math.h>

// Problem constants: B=32 V=512 K=16 D=128 E=32 NE=8192 -> BV=16384 vertices
#define NLSTR 136   // LDS row stride (ushorts) for 16x128 tiles

typedef __bf16 bf16x8 __attribute__((ext_vector_type(8)));
typedef float f32x4 __attribute__((ext_vector_type(4)));
typedef float f32x16 __attribute__((ext_vector_type(16)));
typedef unsigned short ushort8v __attribute__((ext_vector_type(8)));

union FragU { ushort8v u; bf16x8 b; };

static __device__ inline unsigned short f2bf(float f){
  unsigned u = __float_as_uint(f);
  u += 0x7fffu + ((u >> 16) & 1u);   // RNE
  return (unsigned short)(u >> 16);
}
static __device__ inline float bf2f(unsigned short u){
  return __uint_as_float(((unsigned)u) << 16);
}
static __device__ inline unsigned pk2(float a, float b){
  union { __hip_bfloat162 h; unsigned u; } r;
  r.h = __float22bfloat162_rn(float2{a, b});
  return r.u;
}
static __device__ inline ushort8v pkcvt8(float4 a, float4 b){
  union { unsigned u[4]; ushort8v v; } r;
  r.u[0] = pk2(a.x, a.y); r.u[1] = pk2(a.z, a.w);
  r.u[2] = pk2(b.x, b.y); r.u[3] = pk2(b.z, b.w);
  return r.v;
}

// tanh-form GELU (max err ~3e-4 vs exact erf-GELU); exp2 scale folded in.
static __device__ inline float gelu_f(float x){
  float u = x * x;
  float p = fmaf(u, -0.1029434273f, -2.3022084765f);
  float e = __builtin_amdgcn_exp2f(x * p);
  return x * __builtin_amdgcn_rcpf(1.0f + e);
}

// ---------------- prep: bf16 vertex table + fragment-order bf16 weights ----------------
__global__ __launch_bounds__(256) void prep_kernel(
    const float* __restrict__ vf, const float* __restrict__ W1,
    const float* __restrict__ W2, const float* __restrict__ W3,
    unsigned short* __restrict__ vfbf, unsigned short* __restrict__ w1f,
    unsigned short* __restrict__ w2f, unsigned short* __restrict__ w3f)
{
  int t = blockIdx.x * 256 + threadIdx.x;
  if (t < 262144){                       // 16384*128 / 8
    const float4* src = (const float4*)vf;
    float4 x = src[t * 2], y = src[t * 2 + 1];
    *(ushort8v*)(vfbf + t * 8) = pkcvt8(x, y);
    return;
  }
  int t2 = t - 262144;
  const float* s;
  unsigned short* d;
  if (t2 < 2560){                        // w1f: 4nc2 x 10kc strip-major
    int fragid = t2 >> 6, lane = t2 & 63;
    int nc2 = fragid / 10, kc = fragid % 10, n = lane & 31, h = lane >> 5;
    s = W1 + (nc2 * 32 + n) * 160 + kc * 16 + h * 8;
    d = w1f + t2 * 8;
  } else if (t2 < 6656){                 // w2f: 8kc x 8nc
    int t3 = t2 - 2560;
    int fragid = t3 >> 6, lane = t3 & 63;
    int kc = fragid >> 3, nc = fragid & 7, col = lane & 15, quad = lane >> 4;
    s = W2 + (nc * 16 + col) * 256 + kc * 32 + quad * 8;
    d = w2f + t3 * 8;
  } else if (t2 < 8704){                 // w3f: 4kc x 8nc
    int t3 = t2 - 6656;
    int fragid = t3 >> 6, lane = t3 & 63;
    int kc = fragid >> 3, nc = fragid & 7, col = lane & 15, quad = lane >> 4;
    s = W3 + (nc * 16 + col) * 128 + kc * 32 + quad * 8;
    d = w3f + t3 * 8;
  } else return;
#pragma unroll
  for (int j = 0; j < 8; j++) d[j] = f2bf(s[j]);
}

// ---------------- fused ----------------
// grid 1024 x 256thr. Block = 16 vertices = 8 pairs. Stage 1 is LDS-FREE:
// each lane gathers its OWN mfma_32x32x16 A-fragments straight from global
// (row = lane&31 -> neighbor idx; col = kc*16 + h*8 -> 16B load from that
// vertex's vfbf row; edge cols 128-159 gathered as fp32 and packed in-reg).
// ZERO barriers in stage 1: every wave waits only on its own loads via
// compiler-placed incremental vmcnt — no block-wide max-of-768-loads tail per
// phase (the diagnosed 60%-stall cause of the 40us plateau). Pipelining:
// va[kc](p+1) is issued right after MFMA kc consumes va[kc](p); edge loads
// get a full pair (~600cy) of distance. 4 waves re-gather the same rows;
// L1 (32KB) / XCD-L2 (vfbf = 4.2MB table) absorb the redundancy.
__global__ __launch_bounds__(256) void fused_kernel(
    const unsigned short* __restrict__ vfbf,
    const float* __restrict__ vf,
    const int* __restrict__ aadj, const int* __restrict__ badj,
    const float* __restrict__ edge, const float* __restrict__ nbs,
    const float* __restrict__ h0,
    const unsigned short* __restrict__ w1f, const unsigned short* __restrict__ w2f,
    const unsigned short* __restrict__ w3f,
    const float* __restrict__ b1, const float* __restrict__ b2, const float* __restrict__ b3,
    const float* __restrict__ lamda, const float* __restrict__ alpha,
    const int* __restrict__ lval,
    float* __restrict__ out)
{
  __shared__ __align__(16) unsigned short nl_lds[16 * NLSTR];   // 4.25 KB
  __shared__ __align__(16) unsigned short sup_lds[16 * NLSTR];  // 4.25 KB
  const int wid  = threadIdx.x >> 6;
  const int lane = threadIdx.x & 63;
  const int n32  = lane & 31;
  const int h    = lane >> 5;
  const int col  = lane & 15;
  const int quad = lane >> 4;
  const int v0   = blockIdx.x * 16;

  // ---- per-lane adjacency for this lane's A-row (row = lane&31) ----
  // row r of pair p = vertex (v0 + 2p + (r>>4)), slot r&15
  //   -> flat index v0*16 + 32p + r  (r = n32)
  int a_idx[8], e_idx[8];
  {
    const int base = v0 * 16 + n32;
#pragma unroll
    for (int p = 0; p < 8; p++){
      a_idx[p] = aadj[base + 32 * p];
      e_idx[p] = badj[base + 32 * p];
    }
  }

  // ---- B strip into registers (wave wid -> output cols [wid*32,+32)) ----
  FragU bw[10];
#pragma unroll
  for (int kc = 0; kc < 10; kc++)
    bw[kc].u = *(const ushort8v*)(w1f + ((wid * 10 + kc) * 64 + lane) * 8);

  const float bb1 = b1[wid * 32 + n32];
  const float4* nbs4 = (const float4*)nbs;

  // ---- issue pair-0 A gathers ----
  FragU va[8]; float4 ef[4];
  {
    const ushort8v* vs = (const ushort8v*)(vfbf + (size_t)a_idx[0] * 128 + h * 8);
#pragma unroll
    for (int kc = 0; kc < 8; kc++) va[kc].u = vs[2 * kc];
    const float4* es = (const float4*)(edge + (size_t)e_idx[0] * 32 + h * 8);
    ef[0] = es[0]; ef[1] = es[1]; ef[2] = es[4]; ef[3] = es[5];
  }

#pragma unroll
  for (int p = 0; p < 8; ++p){
    const int pn = (p < 7) ? p + 1 : 7;   // last iter re-loads pair 7 (harmless)

    // ---- edge frags for pair p (ef loaded a full pair ago); free ef, reload ----
    FragU ea0, ea1;
    {
      union { unsigned u[4]; ushort8v v; } r0, r1;
      r0.u[0] = pk2(ef[0].x, ef[0].y); r0.u[1] = pk2(ef[0].z, ef[0].w);
      r0.u[2] = pk2(ef[1].x, ef[1].y); r0.u[3] = pk2(ef[1].z, ef[1].w);
      r1.u[0] = pk2(ef[2].x, ef[2].y); r1.u[1] = pk2(ef[2].z, ef[2].w);
      r1.u[2] = pk2(ef[3].x, ef[3].y); r1.u[3] = pk2(ef[3].z, ef[3].w);
      ea0.u = r0.v; ea1.u = r1.v;
    }
    {
      const float4* es = (const float4*)(edge + (size_t)e_idx[pn] * 32 + h * 8);
      ef[0] = es[0]; ef[1] = es[1]; ef[2] = es[4]; ef[3] = es[5];
    }
    const ushort8v* vs = (const ushort8v*)(vfbf + (size_t)a_idx[pn] * 128 + h * 8);

    // ---- MFMA chain; reload va[kc] for pair pn right after its last use ----
    f32x16 acc;
#pragma unroll
    for (int j = 0; j < 16; j++) acc[j] = bb1;
    __builtin_amdgcn_s_setprio(1);
    acc = __builtin_amdgcn_mfma_f32_32x32x16_bf16(va[0].b, bw[0].b, acc, 0, 0, 0); va[0].u = vs[0];
    acc = __builtin_amdgcn_mfma_f32_32x32x16_bf16(va[1].b, bw[1].b, acc, 0, 0, 0); va[1].u = vs[2];
    acc = __builtin_amdgcn_mfma_f32_32x32x16_bf16(va[2].b, bw[2].b, acc, 0, 0, 0); va[2].u = vs[4];
    acc = __builtin_amdgcn_mfma_f32_32x32x16_bf16(va[3].b, bw[3].b, acc, 0, 0, 0); va[3].u = vs[6];
    acc = __builtin_amdgcn_mfma_f32_32x32x16_bf16(va[4].b, bw[4].b, acc, 0, 0, 0); va[4].u = vs[8];
    acc = __builtin_amdgcn_mfma_f32_32x32x16_bf16(va[5].b, bw[5].b, acc, 0, 0, 0); va[5].u = vs[10];
    acc = __builtin_amdgcn_mfma_f32_32x32x16_bf16(va[6].b, bw[6].b, acc, 0, 0, 0); va[6].u = vs[12];
    acc = __builtin_amdgcn_mfma_f32_32x32x16_bf16(va[7].b, bw[7].b, acc, 0, 0, 0); va[7].u = vs[14];
    acc = __builtin_amdgcn_mfma_f32_32x32x16_bf16(ea0.b,  bw[8].b, acc, 0, 0, 0);
    acc = __builtin_amdgcn_mfma_f32_32x32x16_bf16(ea1.b,  bw[9].b, acc, 0, 0, 0);
    __builtin_amdgcn_s_setprio(0);

    // ---- epilogue: GELU, mask, reduce; C row=(reg&3)+8*(reg>>2)+4*h ----
    {
      const int vA = v0 + 2 * p;
      const float4 mAlo = nbs4[vA * 4 + h],       mAhi = nbs4[vA * 4 + 2 + h];
      const float4 mBlo = nbs4[(vA + 1) * 4 + h], mBhi = nbs4[(vA + 1) * 4 + 2 + h];
      float sA = fmaf(gelu_f(acc[0]),  mAlo.x, gelu_f(acc[1])  * mAlo.y)
               + fmaf(gelu_f(acc[2]),  mAlo.z, gelu_f(acc[3])  * mAlo.w)
               + fmaf(gelu_f(acc[4]),  mAhi.x, gelu_f(acc[5])  * mAhi.y)
               + fmaf(gelu_f(acc[6]),  mAhi.z, gelu_f(acc[7])  * mAhi.w);
      float sB = fmaf(gelu_f(acc[8]),  mBlo.x, gelu_f(acc[9])  * mBlo.y)
               + fmaf(gelu_f(acc[10]), mBlo.z, gelu_f(acc[11]) * mBlo.w)
               + fmaf(gelu_f(acc[12]), mBhi.x, gelu_f(acc[13]) * mBhi.y)
               + fmaf(gelu_f(acc[14]), mBhi.z, gelu_f(acc[15]) * mBhi.w);
      sA += __shfl_xor(sA, 32, 64);
      sB += __shfl_xor(sB, 32, 64);
      if (h == 0) nl_lds[(2 * p)     * NLSTR + wid * 32 + n32] = f2bf(sA);
      else        nl_lds[(2 * p + 1) * NLSTR + wid * 32 + n32] = f2bf(sB);
    }
  }
  __syncthreads();   // publish nl_lds (waves were fully independent until here)

  // ---------------- stage 2: wave wid computes output cols [wid*32, wid*32+32) --------
  const int nc0 = 2 * wid;
  const float th = logf(lamda[0] / (float)lval[0] + 1.0f);
  const float al = alpha[0];

  // hoist h0 loads ahead of the MFMA loop
  float h0v[2][4];
#pragma unroll
  for (int pq = 0; pq < 2; pq++){
    const int d = (nc0 + pq) * 16 + col;
#pragma unroll
    for (int r = 0; r < 4; r++)
      h0v[pq][r] = h0[(v0 + quad * 4 + r) * 128 + d];
  }

  f32x4 acc2[2] = {};
#pragma unroll
  for (int kc = 0; kc < 8; kc++){
    FragU a;
    if (kc < 4) a.u = *(const ushort8v*)(nl_lds + col * NLSTR + kc * 32 + quad * 8);
    else        a.u = *(const ushort8v*)(vfbf + (size_t)(v0 + col) * 128 + (kc - 4) * 32 + quad * 8);
#pragma unroll
    for (int pq = 0; pq < 2; pq++){
      FragU bf_;
      bf_.u = *(const ushort8v*)(w2f + ((kc * 8 + nc0 + pq) * 64 + lane) * 8);
      acc2[pq] = __builtin_amdgcn_mfma_f32_16x16x32_bf16(a.b, bf_.b, acc2[pq], 0, 0, 0);
    }
  }

  float sup[2][4];
#pragma unroll
  for (int pq = 0; pq < 2; pq++){
    const int d = (nc0 + pq) * 16 + col;
    const float bb = b2[d];
#pragma unroll
    for (int r = 0; r < 4; r++){
      float hi = acc2[pq][r] + bb;
      float s = (1.f - al) * hi + al * h0v[pq][r];
      sup[pq][r] = s;
      sup_lds[(quad * 4 + r) * NLSTR + d] = f2bf(s);
    }
  }
  __syncthreads();

  // hoist fp32 residual loads (coalesced 64B segments)
  float rv[2][4];
#pragma unroll
  for (int pq = 0; pq < 2; pq++){
    const int d = (nc0 + pq) * 16 + col;
#pragma unroll
    for (int r = 0; r < 4; r++)
      rv[pq][r] = vf[(size_t)(v0 + quad * 4 + r) * 128 + d];
  }

  f32x4 acc3[2] = {};
#pragma unroll
  for (int kc = 0; kc < 4; kc++){
    FragU a;
    a.u = *(const ushort8v*)(sup_lds + col * NLSTR + kc * 32 + quad * 8);
#pragma unroll
    for (int pq = 0; pq < 2; pq++){
      FragU bf_;
      bf_.u = *(const ushort8v*)(w3f + ((kc * 8 + nc0 + pq) * 64 + lane) * 8);
      acc3[pq] = __builtin_amdgcn_mfma_f32_16x16x32_bf16(a.b, bf_.b, acc3[pq], 0, 0, 0);
    }
  }

#pragma unroll
  for (int pq = 0; pq < 2; pq++){
    const int d = (nc0 + pq) * 16 + col;
    const float bb = b3[d];
#pragma unroll
    for (int r = 0; r < 4; r++){
      const int vtx = v0 + quad * 4 + r;
      out[vtx * 128 + d] = th * (acc3[pq][r] + bb) + (1.f - th) * sup[pq][r] + rv[pq][r];
    }
  }
}

extern "C" void kernel_launch(void* const* d_in, const int* in_sizes, int n_in,
                              void* d_out, int out_size, void* d_ws, size_t ws_size,
                              hipStream_t stream)
{
  const float* vfp  = (const float*)d_in[0];
  const int*   aadj = (const int*)d_in[1];
  const int*   badj = (const int*)d_in[2];
  const float* h0   = (const float*)d_in[3];
  const float* lam  = (const float*)d_in[4];
  const float* alp  = (const float*)d_in[5];
  const int*   lv   = (const int*)d_in[6];
  const float* edge = (const float*)d_in[7];
  // d_in[8] vertex_mask: unused by the reference math
  const float* nbs  = (const float*)d_in[9];
  const float* W1   = (const float*)d_in[10];
  const float* b1   = (const float*)d_in[11];
  const float* W2   = (const float*)d_in[12];
  const float* b2   = (const float*)d_in[13];
  const float* W3   = (const float*)d_in[14];
  const float* b3   = (const float*)d_in[15];
  float* out = (float*)d_out;

  // ws layout (ushorts): w1f [0,20480) | w2f [20480,53248) | w3f [53248,69632)
  //                      | vfbf [69632, 69632+2097152)
  unsigned short* w1f  = (unsigned short*)d_ws;
  unsigned short* w2f  = w1f + 20480;
  unsigned short* w3f  = w2f + 32768;
  unsigned short* vfbf = w3f + 16384;

  prep_kernel<<<1058, 256, 0, stream>>>(vfp, W1, W2, W3, vfbf, w1f, w2f, w3f);
  fused_kernel<<<1024, 256, 0, stream>>>(vfbf, vfp, aadj, badj, edge, nbs, h0,
                                         w1f, w2f, w3f, b1, b2, b3, lam, alp, lv, out);
}

// Round 8
// 136.186 us; speedup vs baseline: 1.6715x; 1.2406x over previous
//
#include <hip/hip_runtime.h>
#include <hip/hip_bf16.h>
#include <math.h>

// Problem constants: B=32 V=512 K=16 D=128 E=32 NE=8192 -> BV=16384 vertices
#define NLSTR 136   // LDS row stride (ushorts) for 16x128 tiles
#define ASTR  168   // LDS row stride (ushorts) for A tiles: 160+8 pad, 336B (16B-aligned)

typedef __bf16 bf16x8 __attribute__((ext_vector_type(8)));
typedef float f32x4 __attribute__((ext_vector_type(4)));
typedef float f32x16 __attribute__((ext_vector_type(16)));
typedef unsigned short ushort8v __attribute__((ext_vector_type(8)));

union FragU { ushort8v u; bf16x8 b; };

static __device__ inline unsigned short f2bf(float f){
  unsigned u = __float_as_uint(f);
  u += 0x7fffu + ((u >> 16) & 1u);   // RNE
  return (unsigned short)(u >> 16);
}
static __device__ inline unsigned pk2(float a, float b){
  union { __hip_bfloat162 h; unsigned u; } r;
  r.h = __float22bfloat162_rn(float2{a, b});
  return r.u;
}
static __device__ inline ushort8v pkcvt8(float4 a, float4 b){
  union { unsigned u[4]; ushort8v v; } r;
  r.u[0] = pk2(a.x, a.y); r.u[1] = pk2(a.z, a.w);
  r.u[2] = pk2(b.x, b.y); r.u[3] = pk2(b.z, b.w);
  return r.v;
}

// tanh-form GELU (max err ~3e-4 vs exact erf-GELU); exp2 scale folded in.
static __device__ inline float gelu_f(float x){
  float u = x * x;
  float p = fmaf(u, -0.1029434273f, -2.3022084765f);
  float e = __builtin_amdgcn_exp2f(x * p);
  return x * __builtin_amdgcn_rcpf(1.0f + e);
}

// Raw barrier: publishes own LDS writes (lgkmcnt drain) WITHOUT draining vmcnt.
#define WG_BARRIER() asm volatile("s_waitcnt lgkmcnt(0)\n\ts_barrier" ::: "memory")

// ---------------- prep: bf16 vertex table + fragment-order bf16 weights ----------------
// (identical to R3-passed version; workspace layout unchanged from R0-R6)
__global__ __launch_bounds__(256) void prep_kernel(
    const float* __restrict__ vf, const float* __restrict__ W1,
    const float* __restrict__ W2, const float* __restrict__ W3,
    unsigned short* __restrict__ vfbf, unsigned short* __restrict__ w1f,
    unsigned short* __restrict__ w2f, unsigned short* __restrict__ w3f)
{
  int t = blockIdx.x * 256 + threadIdx.x;
  if (t < 262144){                       // 16384*128 / 8
    const float4* src = (const float4*)vf;
    float4 x = src[t * 2], y = src[t * 2 + 1];
    *(ushort8v*)(vfbf + t * 8) = pkcvt8(x, y);
    return;
  }
  int t2 = t - 262144;
  const float* s;
  unsigned short* d;
  if (t2 < 2560){                        // w1f: 4nc2 x 10kc strip-major
    int fragid = t2 >> 6, lane = t2 & 63;
    int nc2 = fragid / 10, kc = fragid % 10, n = lane & 31, h = lane >> 5;
    s = W1 + (nc2 * 32 + n) * 160 + kc * 16 + h * 8;
    d = w1f + t2 * 8;
  } else if (t2 < 6656){                 // w2f: 8kc x 8nc
    int t3 = t2 - 2560;
    int fragid = t3 >> 6, lane = t3 & 63;
    int kc = fragid >> 3, nc = fragid & 7, col = lane & 15, quad = lane >> 4;
    s = W2 + (nc * 16 + col) * 256 + kc * 32 + quad * 8;
    d = w2f + t3 * 8;
  } else if (t2 < 8704){                 // w3f: 4kc x 8nc
    int t3 = t2 - 6656;
    int fragid = t3 >> 6, lane = t3 & 63;
    int kc = fragid >> 3, nc = fragid & 7, col = lane & 15, quad = lane >> 4;
    s = W3 + (nc * 16 + col) * 128 + kc * 32 + quad * 8;
    d = w3f + t3 * 8;
  } else return;
#pragma unroll
  for (int j = 0; j < 8; j++) d[j] = f2bf(s[j]);
}

// ---------------- fused ----------------
// grid 1024 x 256thr. Block = 16 vertices = 8 pairs, TWO 4-pair batches (R3
// structure, best measured). Theory under test: the 268MB harness fill evicts
// L2+L3 every iteration, so gathers demand-miss cold (FETCH 42MB = 8 XCDs x
// full gather region, random 16B misses ~900cy). Fix: cooperative L2 warm-up —
// blockIdx%8 = XCD (round-robin); blocks 8s..8s+7 (one per XCD) stream slice s
// of vfbf (4MB, 8 float4/thread) + edge f32 (1MB, 2 float4/thread) with
// coalesced loads; the 128 resident blocks per XCD cover the whole region at
// streaming BW. Keep-alive asm sits BEFORE the gather issues so the 10 warm-up
// regs die before sv/se go live (peak VGPR stays at R3's proven level).
__global__ __launch_bounds__(256, 3) void fused_kernel(
    const unsigned short* __restrict__ vfbf,
    const float* __restrict__ vf,
    const int* __restrict__ aadj, const int* __restrict__ badj,
    const float* __restrict__ edge, const float* __restrict__ nbs,
    const float* __restrict__ h0,
    const unsigned short* __restrict__ w1f, const unsigned short* __restrict__ w2f,
    const unsigned short* __restrict__ w3f,
    const float* __restrict__ b1, const float* __restrict__ b2, const float* __restrict__ b3,
    const float* __restrict__ lamda, const float* __restrict__ alpha,
    const int* __restrict__ lval,
    float* __restrict__ out)
{
  __shared__ __align__(16) unsigned short abuf[4][32 * ASTR];   // 4 x 10.5 KB
  __shared__ __align__(16) unsigned short nl_lds[16 * NLSTR];
  __shared__ __align__(16) unsigned short sup_lds[16 * NLSTR];
  __shared__ __align__(16) float nbs_lds[256];                  // 16 vertices x 16 masks
  const int wid  = threadIdx.x >> 6;
  const int lane = threadIdx.x & 63;
  const int n32  = lane & 31;
  const int h    = lane >> 5;
  const int col  = lane & 15;
  const int quad = lane >> 4;
  const int v0   = blockIdx.x * 16;

  // staging thread mapping: 8 threads per A row
  const int srow = threadIdx.x >> 3;   // 0..31: row (vertex-half + neighbor slot)
  const int ssub = threadIdx.x & 7;    // 0..7

  // ---- L2 warm-up: slice s = blockIdx>>3 (0..127), one block per XCD per slice.
  // vfbf: 262144 float4 -> 2048/slice (8/thread). edge: 65536 float4 -> 512/slice (2/thread).
  float4 wu[10];
  {
    const float4* vsrc = (const float4*)vfbf;
    const int vb = (blockIdx.x >> 3) * 2048 + threadIdx.x;
#pragma unroll
    for (int i = 0; i < 8; i++) wu[i] = vsrc[vb + i * 256];
    const float4* esrc = (const float4*)edge;
    const int eb = (blockIdx.x >> 3) * 512 + threadIdx.x;
    wu[8] = esrc[eb]; wu[9] = esrc[eb + 256];
  }

  // ---- stage nbs masks into LDS (published by first barrier) ----
  nbs_lds[threadIdx.x] = nbs[v0 * 16 + threadIdx.x];

  // ---- preload ALL pair indices (coalesced; kills idx->gather chain) ----
  int a_all[8], e_all[8];
  {
    const int base = (v0 + (srow >> 4)) * 16 + (srow & 15);
#pragma unroll
    for (int p = 0; p < 8; p++){
      a_all[p] = aadj[base + 32 * p];
      e_all[p] = badj[base + 32 * p];
    }
  }

  // keep warm-up values alive (prevents DCE; frees the 10 regs before sv/se live)
#pragma unroll
  for (int i = 0; i < 10; i++)
    asm volatile("" :: "v"(wu[i].x), "v"(wu[i].y), "v"(wu[i].z), "v"(wu[i].w));

  ushort8v sv[4][2]; float4 se[4];
  // ---- issue batch-0 gathers (pairs 0..3) ----
#pragma unroll
  for (int q = 0; q < 4; q++){
    const ushort8v* vs = (const ushort8v*)(vfbf + (size_t)a_all[q] * 128 + ssub * 16);
    sv[q][0] = vs[0]; sv[q][1] = vs[1];
    se[q] = *(const float4*)(edge + (size_t)e_all[q] * 32 + ssub * 4);
  }

  // ---- B strip into registers while gathers fly (wave wid -> cols [wid*32,+32)) ----
  FragU bw[10];
#pragma unroll
  for (int kc = 0; kc < 10; kc++)
    bw[kc].u = *(const ushort8v*)(w1f + ((wid * 10 + kc) * 64 + lane) * 8);

  const float bb1 = b1[wid * 32 + n32];

  // ---- commit batch 0 (vmcnt waits happen here, once per batch) ----
#pragma unroll
  for (int q = 0; q < 4; q++){
    unsigned short* dst = abuf[q] + srow * ASTR + ssub * 16;
    *(ushort8v*)dst = sv[q][0]; *(ushort8v*)(dst + 8) = sv[q][1];
    unsigned* ed = (unsigned*)(abuf[q] + srow * ASTR + 128 + ssub * 4);
    ed[0] = pk2(se[q].x, se[q].y); ed[1] = pk2(se[q].z, se[q].w);
  }
  WG_BARRIER();   // publish batch 0 + nbs_lds

  // ---- issue batch-1 gathers (pairs 4..7); land during batch-0 compute ----
#pragma unroll
  for (int q = 0; q < 4; q++){
    const ushort8v* vs = (const ushort8v*)(vfbf + (size_t)a_all[q + 4] * 128 + ssub * 16);
    sv[q][0] = vs[0]; sv[q][1] = vs[1];
    se[q] = *(const float4*)(edge + (size_t)e_all[q + 4] * 32 + ssub * 4);
  }

  const float4* nbsl = (const float4*)nbs_lds;

  // ================= compute batch 0: pairs 0..3, barrier-free =================
#pragma unroll
  for (int p = 0; p < 4; p++){
    const float4 mAlo = nbsl[8 * p + h],     mAhi = nbsl[8 * p + 2 + h];
    const float4 mBlo = nbsl[8 * p + 4 + h], mBhi = nbsl[8 * p + 6 + h];
    const unsigned short* ab = abuf[p] + n32 * ASTR + h * 8;
    f32x16 acc;
#pragma unroll
    for (int j = 0; j < 16; j++) acc[j] = bb1;
#pragma unroll
    for (int kc = 0; kc < 10; kc++){
      FragU fa;
      fa.u = *(const ushort8v*)(ab + kc * 16);
      acc = __builtin_amdgcn_mfma_f32_32x32x16_bf16(fa.b, bw[kc].b, acc, 0, 0, 0);
    }
    float sA = fmaf(gelu_f(acc[0]),  mAlo.x, gelu_f(acc[1])  * mAlo.y)
             + fmaf(gelu_f(acc[2]),  mAlo.z, gelu_f(acc[3])  * mAlo.w)
             + fmaf(gelu_f(acc[4]),  mAhi.x, gelu_f(acc[5])  * mAhi.y)
             + fmaf(gelu_f(acc[6]),  mAhi.z, gelu_f(acc[7])  * mAhi.w);
    float sB = fmaf(gelu_f(acc[8]),  mBlo.x, gelu_f(acc[9])  * mBlo.y)
             + fmaf(gelu_f(acc[10]), mBlo.z, gelu_f(acc[11]) * mBlo.w)
             + fmaf(gelu_f(acc[12]), mBhi.x, gelu_f(acc[13]) * mBhi.y)
             + fmaf(gelu_f(acc[14]), mBhi.z, gelu_f(acc[15]) * mBhi.w);
    sA += __shfl_xor(sA, 32, 64);
    sB += __shfl_xor(sB, 32, 64);
    if (h == 0) nl_lds[(2 * p)     * NLSTR + wid * 32 + n32] = f2bf(sA);
    else        nl_lds[(2 * p + 1) * NLSTR + wid * 32 + n32] = f2bf(sB);
  }
  WG_BARRIER();   // all waves done reading abuf

  // ---- commit batch 1 ----
#pragma unroll
  for (int q = 0; q < 4; q++){
    unsigned short* dst = abuf[q] + srow * ASTR + ssub * 16;
    *(ushort8v*)dst = sv[q][0]; *(ushort8v*)(dst + 8) = sv[q][1];
    unsigned* ed = (unsigned*)(abuf[q] + srow * ASTR + 128 + ssub * 4);
    ed[0] = pk2(se[q].x, se[q].y); ed[1] = pk2(se[q].z, se[q].w);
  }
  WG_BARRIER();   // publish batch 1

  // ================= compute batch 1: pairs 4..7 =================
#pragma unroll
  for (int p = 0; p < 4; p++){
    const int pp = p + 4;
    const float4 mAlo = nbsl[8 * pp + h],     mAhi = nbsl[8 * pp + 2 + h];
    const float4 mBlo = nbsl[8 * pp + 4 + h], mBhi = nbsl[8 * pp + 6 + h];
    const unsigned short* ab = abuf[p] + n32 * ASTR + h * 8;
    f32x16 acc;
#pragma unroll
    for (int j = 0; j < 16; j++) acc[j] = bb1;
#pragma unroll
    for (int kc = 0; kc < 10; kc++){
      FragU fa;
      fa.u = *(const ushort8v*)(ab + kc * 16);
      acc = __builtin_amdgcn_mfma_f32_32x32x16_bf16(fa.b, bw[kc].b, acc, 0, 0, 0);
    }
    float sA = fmaf(gelu_f(acc[0]),  mAlo.x, gelu_f(acc[1])  * mAlo.y)
             + fmaf(gelu_f(acc[2]),  mAlo.z, gelu_f(acc[3])  * mAlo.w)
             + fmaf(gelu_f(acc[4]),  mAhi.x, gelu_f(acc[5])  * mAhi.y)
             + fmaf(gelu_f(acc[6]),  mAhi.z, gelu_f(acc[7])  * mAhi.w);
    float sB = fmaf(gelu_f(acc[8]),  mBlo.x, gelu_f(acc[9])  * mBlo.y)
             + fmaf(gelu_f(acc[10]), mBlo.z, gelu_f(acc[11]) * mBlo.w)
             + fmaf(gelu_f(acc[12]), mBhi.x, gelu_f(acc[13]) * mBhi.y)
             + fmaf(gelu_f(acc[14]), mBhi.z, gelu_f(acc[15]) * mBhi.w);
    sA += __shfl_xor(sA, 32, 64);
    sB += __shfl_xor(sB, 32, 64);
    if (h == 0) nl_lds[(2 * pp)     * NLSTR + wid * 32 + n32] = f2bf(sA);
    else        nl_lds[(2 * pp + 1) * NLSTR + wid * 32 + n32] = f2bf(sB);
  }
  __syncthreads();

  // ---------------- stage 2: wave wid computes output cols [wid*32, wid*32+32) --------
  const int nc0 = 2 * wid;
  const float th = logf(lamda[0] / (float)lval[0] + 1.0f);
  const float al = alpha[0];

  float h0v[2][4];
#pragma unroll
  for (int pq = 0; pq < 2; pq++){
    const int d = (nc0 + pq) * 16 + col;
#pragma unroll
    for (int r = 0; r < 4; r++)
      h0v[pq][r] = h0[(v0 + quad * 4 + r) * 128 + d];
  }

  f32x4 acc2[2] = {};
#pragma unroll
  for (int kc = 0; kc < 8; kc++){
    FragU a;
    if (kc < 4) a.u = *(const ushort8v*)(nl_lds + col * NLSTR + kc * 32 + quad * 8);
    else        a.u = *(const ushort8v*)(vfbf + (size_t)(v0 + col) * 128 + (kc - 4) * 32 + quad * 8);
#pragma unroll
    for (int pq = 0; pq < 2; pq++){
      FragU bf_;
      bf_.u = *(const ushort8v*)(w2f + ((kc * 8 + nc0 + pq) * 64 + lane) * 8);
      acc2[pq] = __builtin_amdgcn_mfma_f32_16x16x32_bf16(a.b, bf_.b, acc2[pq], 0, 0, 0);
    }
  }

  float sup[2][4];
#pragma unroll
  for (int pq = 0; pq < 2; pq++){
    const int d = (nc0 + pq) * 16 + col;
    const float bb = b2[d];
#pragma unroll
    for (int r = 0; r < 4; r++){
      float hi = acc2[pq][r] + bb;
      float s = (1.f - al) * hi + al * h0v[pq][r];
      sup[pq][r] = s;
      sup_lds[(quad * 4 + r) * NLSTR + d] = f2bf(s);
    }
  }
  __syncthreads();

  float rv[2][4];
#pragma unroll
  for (int pq = 0; pq < 2; pq++){
    const int d = (nc0 + pq) * 16 + col;
#pragma unroll
    for (int r = 0; r < 4; r++)
      rv[pq][r] = vf[(size_t)(v0 + quad * 4 + r) * 128 + d];
  }

  f32x4 acc3[2] = {};
#pragma unroll
  for (int kc = 0; kc < 4; kc++){
    FragU a;
    a.u = *(const ushort8v*)(sup_lds + col * NLSTR + kc * 32 + quad * 8);
#pragma unroll
    for (int pq = 0; pq < 2; pq++){
      FragU bf_;
      bf_.u = *(const ushort8v*)(w3f + ((kc * 8 + nc0 + pq) * 64 + lane) * 8);
      acc3[pq] = __builtin_amdgcn_mfma_f32_16x16x32_bf16(a.b, bf_.b, acc3[pq], 0, 0, 0);
    }
  }

#pragma unroll
  for (int pq = 0; pq < 2; pq++){
    const int d = (nc0 + pq) * 16 + col;
    const float bb = b3[d];
#pragma unroll
    for (int r = 0; r < 4; r++){
      const int vtx = v0 + quad * 4 + r;
      out[vtx * 128 + d] = th * (acc3[pq][r] + bb) + (1.f - th) * sup[pq][r] + rv[pq][r];
    }
  }
}

extern "C" void kernel_launch(void* const* d_in, const int* in_sizes, int n_in,
                              void* d_out, int out_size, void* d_ws, size_t ws_size,
                              hipStream_t stream)
{
  const float* vfp  = (const float*)d_in[0];
  const int*   aadj = (const int*)d_in[1];
  const int*   badj = (const int*)d_in[2];
  const float* h0   = (const float*)d_in[3];
  const float* lam  = (const float*)d_in[4];
  const float* alp  = (const float*)d_in[5];
  const int*   lv   = (const int*)d_in[6];
  const float* edge = (const float*)d_in[7];
  // d_in[8] vertex_mask: unused by the reference math
  const float* nbs  = (const float*)d_in[9];
  const float* W1   = (const float*)d_in[10];
  const float* b1   = (const float*)d_in[11];
  const float* W2   = (const float*)d_in[12];
  const float* b2   = (const float*)d_in[13];
  const float* W3   = (const float*)d_in[14];
  const float* b3   = (const float*)d_in[15];
  float* out = (float*)d_out;

  // ws layout (ushorts): w1f [0,20480) | w2f [20480,53248) | w3f [53248,69632)
  //                      | vfbf [69632, 69632+2097152)     (identical to R0-R6)
  unsigned short* w1f  = (unsigned short*)d_ws;
  unsigned short* w2f  = w1f + 20480;
  unsigned short* w3f  = w2f + 32768;
  unsigned short* vfbf = w3f + 16384;

  prep_kernel<<<1058, 256, 0, stream>>>(vfp, W1, W2, W3, vfbf, w1f, w2f, w3f);
  fused_kernel<<<1024, 256, 0, stream>>>(vfbf, vfp, aadj, badj, edge, nbs, h0,
                                         w1f, w2f, w3f, b1, b2, b3, lam, alp, lv, out);
}